// Round 8
// baseline (1090.888 us; speedup 1.0000x reference)
//
#include <hip/hip_runtime.h>

#define TT 512
#define DD 64
#define BB 1024
#define PF 8               // prefetch depth (steps) in the recurrence
#define HH 8
#define WBLK 32            // window (timesteps) per barrier interval
#define XPAD 68            // padded LDS row stride for producer staging

__device__ __forceinline__ float fexp2(float x){ return __builtin_amdgcn_exp2f(x); }
__device__ __forceinline__ float frcp (float x){ return __builtin_amdgcn_rcpf(x); }

// DPP: quad_perm uniform selectors (direction-proof) and row_ror:4k whose
// direction is resolved by a runtime probe.
template<int C>
__device__ __forceinline__ float dppf(float x){
  return __int_as_float(__builtin_amdgcn_update_dpp(0, __float_as_int(x), C, 0xF, 0xF, true));
}
template<int C>
__device__ __forceinline__ int dppi(int x){
  return __builtin_amdgcn_update_dpp(0, x, C, 0xF, 0xF, true);
}

// lane^16 exchange within each 32-lane group (BitMode: and=0x1F, or=0, xor=0x10)
__device__ __forceinline__ float swz16(float x){
  return __int_as_float(__builtin_amdgcn_ds_swizzle(__float_as_int(x), 0x401F));
}

template<int N> struct IC { static constexpr int v = N; };

// ============================================================
// FUSED kernel v2 (resubmit of round 7 — round-7 bench was an infra
// failure with no counters; structure audited deadlock-free):
// producer waves write the layer-0 projection P to GLOBAL memory (d_ws)
// 2 windows ahead; consumer waves run the VERBATIM v4 recurrence (global
// P reads, 8-deep vmcnt prefetch) with one barrier per 32-step window.
//   - P on vmcnt: consumer lgkm counter carries ONLY the 3 swizzles per
//     step (round-6's +186cyc/step came from P-LDS reads sharing the
//     in-order lgkm queue with critical-path ds_swizzle).
//   - producer x staging padded to stride 68: broadcast reads conflict-free
//     (round-6 had 1.678e7 LDS bank conflicts).
//   - visibility: __syncthreads drains vmcnt(0); each P address is read
//     exactly once per launch.
// 256 blocks x 256 threads, 1 block/CU (forced via 96 KiB dynamic LDS —
// the same launch config that ran and PASSED in round 6).
// Waves 0-1: consumers (4 elems). Waves 2-3: producers (2 elems each).
// Schedule: warmup {item0,item1}; barrier; win=0..31: {producer item win+2
// | consumer window win}; barrier.  Items/windows 0..15 = encoder,
// 16..31 = decoder.  All P values (v5 math) and consumer arithmetic (v4
// order) bit-identical to verified kernels -> absmax 0.0.
// ============================================================
__global__ __launch_bounds__(256) void fused_kernel(
    const float* __restrict__ x,
    const float* __restrict__ h0,    const float* __restrict__ c0,
    const float* __restrict__ eWih0, const float* __restrict__ eWihR, const float* __restrict__ eWhh,
    const float* __restrict__ eBih,  const float* __restrict__ eBhh,
    const float* __restrict__ dWih0, const float* __restrict__ dWihR, const float* __restrict__ dWhh,
    const float* __restrict__ dBih,  const float* __restrict__ dBhh,
    const float* __restrict__ linW,  const float* __restrict__ linB,
    float* __restrict__ P,
    float* __restrict__ out)
{
  extern __shared__ __align__(16) float smem[];   // producer staging only

  const int tid  = threadIdx.x;
  const int wv   = tid >> 6;
  const int lane = tid & 63;
  const bool prod = (wv >= 2);

  // ---------------- consumer lane mapping (waves 0-1) ----------------
  const int idx = tid & 31;          // within-elem lane
  const int v   = idx >> 2;          // unit 0..7
  const int g   = idx & 3;           // torch gate (i,f,g,o)
  const int b   = v & 3;             // rotation base (low-col index)
  const bool rB = (v >= 4);          // DPP row-1 lanes
  const int erow = tid >> 5;         // 0..3 for consumers
  const int e    = blockIdx.x * 4 + erow;

  const bool is_tanh = (g == 2);
  const float ns_act = is_tanh ? -2.885390082f : -1.44269504f;
  const float a_act  = is_tanh ? 2.0f : 1.0f;
  const float b_act  = is_tanh ? -1.0f : 0.0f;

  // runtime direction probe for row_ror:4 (wave-uniform d = 1 or 3)
  const int qidx = (tid >> 2) & 3;
  const int p4 = dppi<0x124>(qidx);
  const int d  = __builtin_amdgcn_readfirstlane((p4 - qidx) & 3);

  float H[3], cs[3], sd[3];
  float bd1 = 0.f, bd2 = 0.f;
  float pf[PF];
  float WS[3][8], WBr[2][8], Bss[2];

  if (!prod) {
#pragma unroll
    for (int l = 0; l < 3; ++l) {
      H[l]  = h0[((size_t)l * BB + e) * HH + v];
      cs[l] = c0[((size_t)l * BB + e) * HH + v];
    }
  }

  // ---------------- producer lane mapping (waves 2-3) ----------------
  const int rsel = lane >> 4;        // row-in-chunk 0..3
  const int m    = lane & 15;        // slot pair {2m, 2m+1}
  const int r_even = (m >> 2) * 8 + (m & 3);
  const int r_odd  = r_even + 4;
  const int p0 = (wv - 2) * 2;       // first of my 2 elems
  float* xp = smem + (wv & 1) * (WBLK * XPAD);   // per-wave padded staging
  float Wa[64], Wb[64];
  float bA = 0.f, bB = 0.f;
  int curph = 0;

  auto loadW = [&](int ph) {
    const float* W  = ph ? dWih0 : eWih0;
    const float* Bi = ph ? dBih  : eBih;
    const float* Bh = ph ? dBhh  : eBhh;
    bA = Bi[r_even] + Bh[r_even];
    bB = Bi[r_odd]  + Bh[r_odd];
#pragma unroll
    for (int k = 0; k < 16; ++k) {
      float4 wq = *(const float4*)(W + r_even * 64 + k * 4);
      Wa[k*4+0] = wq.x; Wa[k*4+1] = wq.y; Wa[k*4+2] = wq.z; Wa[k*4+3] = wq.w;
    }
#pragma unroll
    for (int k = 0; k < 16; ++k) {
      float4 wq = *(const float4*)(W + r_odd * 64 + k * 4);
      Wb[k*4+0] = wq.x; Wb[k*4+1] = wq.y; Wb[k*4+2] = wq.z; Wb[k*4+3] = wq.w;
    }
  };

  // produce one 32-step window of P for my 2 elems (v5 math, bit-exact)
  auto produce = [&](int ph, int w) {
    if (ph != curph) { loadW(ph); curph = ph; }
#pragma unroll 1
    for (int es = 0; es < 2; ++es) {
      const int p  = p0 + es;
      const int eE = blockIdx.x * 4 + p;
      const float* xg = x + ((size_t)eE * TT + w * WBLK) * 64;
      float4 sv[8];
#pragma unroll
      for (int i = 0; i < 8; ++i) sv[i] = *(const float4*)(xg + i * 256 + lane * 4);
#pragma unroll
      for (int i = 0; i < 8; ++i)
        *(float4*)(xp + (i * 4 + (lane >> 4)) * XPAD + 4 * (lane & 15)) = sv[i];
#pragma unroll 1
      for (int ci = 0; ci < 8; ++ci) {
        const int rib = ci * 4 + rsel;
        const float* xr = xp + rib * XPAD;
        float a0A = bA, a1A = 0.f, a2A = 0.f, a3A = 0.f;
        float a0B = bB, a1B = 0.f, a2B = 0.f, a3B = 0.f;
#pragma unroll
        for (int kc = 0; kc < 16; ++kc) {
          float4 xv = *(const float4*)(xr + kc * 4);
          a0A = fmaf(Wa[kc*4+0], xv.x, a0A);
          a1A = fmaf(Wa[kc*4+1], xv.y, a1A);
          a2A = fmaf(Wa[kc*4+2], xv.z, a2A);
          a3A = fmaf(Wa[kc*4+3], xv.w, a3A);
          a0B = fmaf(Wb[kc*4+0], xv.x, a0B);
          a1B = fmaf(Wb[kc*4+1], xv.y, a1B);
          a2B = fmaf(Wb[kc*4+2], xv.z, a2B);
          a3B = fmaf(Wb[kc*4+3], xv.w, a3B);
        }
        float2 res;
        res.x = (a0A + a1A) + (a2A + a3A);
        res.y = (a0B + a1B) + (a2B + a3B);
        *(float2*)(P + ((size_t)((ph << 10) + eE) * TT + (w * WBLK + rib)) * 32 + 2 * m) = res;
      }
    }
  };

  // ---------------- consumer helpers (verbatim v4) ----------------
  auto bcast = [&](float hn, float* A, float* Bv) {
    float Hsw = swz16(hn);
    float Lo = rB ? Hsw : hn;
    float Hi = rB ? hn : Hsw;
    A[0]  = Lo; A[1]  = dppf<0x124>(Lo); A[2]  = dppf<0x128>(Lo); A[3]  = dppf<0x12C>(Lo);
    Bv[0] = Hi; Bv[1] = dppf<0x124>(Hi); Bv[2] = dppf<0x128>(Hi); Bv[3] = dppf<0x12C>(Hi);
  };

  auto load_phase = [&](const float* WihR, const float* Whh,
                        const float* Bih, const float* Bhh) {
#pragma unroll
    for (int l = 0; l < 3; ++l) {
      const int r0 = l * 32 + g * 8 + v;
#pragma unroll
      for (int k = 0; k < 4; ++k) {
        const int col = (b + d * k) & 3;
        WS[l][k]     = Whh[r0 * 8 + col];
        WS[l][4 + k] = Whh[r0 * 8 + 4 + col];
      }
    }
#pragma unroll
    for (int l = 0; l < 2; ++l) {
      const int r0 = l * 32 + g * 8 + v;
#pragma unroll
      for (int k = 0; k < 4; ++k) {
        const int col = (b + d * k) & 3;
        WBr[l][k]     = WihR[r0 * 8 + col];
        WBr[l][4 + k] = WihR[r0 * 8 + 4 + col];
      }
      Bss[l] = Bih[(l + 1) * 32 + g * 8 + v] + Bhh[(l + 1) * 32 + g * 8 + v];
    }
#pragma unroll
    for (int l = 0; l < 3; ++l) {
      float A[4], Bv[4];
      bcast(H[l], A, Bv);
      float acc = l ? Bss[l - 1] : 0.f;
#pragma unroll
      for (int k = 0; k < 4; ++k) {
        acc = fmaf(WS[l][k],     A[k],  acc);
        acc = fmaf(WS[l][4 + k], Bv[k], acc);
      }
      sd[l] = acc;
    }
  };

  auto lstep = [&](auto LC, float in) -> float {
    constexpr int l = decltype(LC)::v;
    float pre = in + sd[l];
    float ex  = fexp2(ns_act * pre);
    float rc  = frcp(1.f + ex);
    float act = fmaf(a_act, rc, b_act);
    float Gi = dppf<0x00>(act);
    float Gf = dppf<0x55>(act);
    float Gg = dppf<0xAA>(act);
    float Go = dppf<0xFF>(act);
    float cn = fmaf(Gf, cs[l], Gi * Gg);
    cs[l] = cn;
    float tx = fexp2(-2.885390082f * cn);
    float tr = frcp(1.f + tx);
    float th = fmaf(2.f, tr, -1.f);
    float hn = Go * th;
    H[l] = hn;
    float A[4], Bv[4];
    bcast(hn, A, Bv);
    float accS;
    if constexpr (l > 0) accS = Bss[l - 1]; else accS = 0.f;
#pragma unroll
    for (int k = 0; k < 4; ++k) {
      accS = fmaf(WS[l][k],     A[k],  accS);
      accS = fmaf(WS[l][4 + k], Bv[k], accS);
    }
    sd[l] = accS;
    float accB = 0.f;
    if constexpr (l < 2) {
#pragma unroll
      for (int k = 0; k < 4; ++k) {
        accB = fmaf(WBr[l][k],     A[k],  accB);
        accB = fmaf(WBr[l][4 + k], Bv[k], accB);
      }
    }
    return accB;
  };

  auto lstep3 = [&](float in0, float in1, float in2, float& nb1, float& nb2) {
    float pre0 = in0 + sd[0];
    float pre1 = in1 + sd[1];
    float pre2 = in2 + sd[2];
    float ex0 = fexp2(ns_act * pre0);
    float ex1 = fexp2(ns_act * pre1);
    float ex2 = fexp2(ns_act * pre2);
    float rc0 = frcp(1.f + ex0);
    float rc1 = frcp(1.f + ex1);
    float rc2 = frcp(1.f + ex2);
    float ac0 = fmaf(a_act, rc0, b_act);
    float ac1 = fmaf(a_act, rc1, b_act);
    float ac2 = fmaf(a_act, rc2, b_act);
    float Gi0 = dppf<0x00>(ac0), Gi1 = dppf<0x00>(ac1), Gi2 = dppf<0x00>(ac2);
    float Gf0 = dppf<0x55>(ac0), Gf1 = dppf<0x55>(ac1), Gf2 = dppf<0x55>(ac2);
    float Gg0 = dppf<0xAA>(ac0), Gg1 = dppf<0xAA>(ac1), Gg2 = dppf<0xAA>(ac2);
    float Go0 = dppf<0xFF>(ac0), Go1 = dppf<0xFF>(ac1), Go2 = dppf<0xFF>(ac2);
    float cn0 = fmaf(Gf0, cs[0], Gi0 * Gg0);
    float cn1 = fmaf(Gf1, cs[1], Gi1 * Gg1);
    float cn2 = fmaf(Gf2, cs[2], Gi2 * Gg2);
    cs[0] = cn0; cs[1] = cn1; cs[2] = cn2;
    float tx0 = fexp2(-2.885390082f * cn0);
    float tx1 = fexp2(-2.885390082f * cn1);
    float tx2 = fexp2(-2.885390082f * cn2);
    float tr0 = frcp(1.f + tx0);
    float tr1 = frcp(1.f + tx1);
    float tr2 = frcp(1.f + tx2);
    float th0 = fmaf(2.f, tr0, -1.f);
    float th1 = fmaf(2.f, tr1, -1.f);
    float th2 = fmaf(2.f, tr2, -1.f);
    float hn0 = Go0 * th0;
    float hn1 = Go1 * th1;
    float hn2 = Go2 * th2;
    H[0] = hn0; H[1] = hn1; H[2] = hn2;
    float sw0 = swz16(hn0);
    float sw1 = swz16(hn1);
    float sw2 = swz16(hn2);
    float Lo0 = rB ? sw0 : hn0, Hi0 = rB ? hn0 : sw0;
    float Lo1 = rB ? sw1 : hn1, Hi1 = rB ? hn1 : sw1;
    float Lo2 = rB ? sw2 : hn2, Hi2 = rB ? hn2 : sw2;
    float A0[4], B0[4], A1[4], B1[4], A2[4], B2[4];
    A0[0] = Lo0; A0[1] = dppf<0x124>(Lo0); A0[2] = dppf<0x128>(Lo0); A0[3] = dppf<0x12C>(Lo0);
    B0[0] = Hi0; B0[1] = dppf<0x124>(Hi0); B0[2] = dppf<0x128>(Hi0); B0[3] = dppf<0x12C>(Hi0);
    A1[0] = Lo1; A1[1] = dppf<0x124>(Lo1); A1[2] = dppf<0x128>(Lo1); A1[3] = dppf<0x12C>(Lo1);
    B1[0] = Hi1; B1[1] = dppf<0x124>(Hi1); B1[2] = dppf<0x128>(Hi1); B1[3] = dppf<0x12C>(Hi1);
    A2[0] = Lo2; A2[1] = dppf<0x124>(Lo2); A2[2] = dppf<0x128>(Lo2); A2[3] = dppf<0x12C>(Lo2);
    B2[0] = Hi2; B2[1] = dppf<0x124>(Hi2); B2[2] = dppf<0x128>(Hi2); B2[3] = dppf<0x12C>(Hi2);
    float s0 = 0.f, s1 = Bss[0], s2 = Bss[1];
    float u0 = 0.f, u1 = 0.f;
#pragma unroll
    for (int k = 0; k < 4; ++k) {
      s0 = fmaf(WS[0][k],     A0[k], s0);
      s0 = fmaf(WS[0][4 + k], B0[k], s0);
      s1 = fmaf(WS[1][k],     A1[k], s1);
      s1 = fmaf(WS[1][4 + k], B1[k], s1);
      s2 = fmaf(WS[2][k],     A2[k], s2);
      s2 = fmaf(WS[2][4 + k], B2[k], s2);
      u0 = fmaf(WBr[0][k],     A0[k], u0);
      u0 = fmaf(WBr[0][4 + k], B0[k], u0);
      u1 = fmaf(WBr[1][k],     A1[k], u1);
      u1 = fmaf(WBr[1][4 + k], B1[k], u1);
    }
    sd[0] = s0; sd[1] = s1; sd[2] = s2;
    nb1 = u0; nb2 = u1;
  };

  const int pos_c = (g * 4 + b) * 2 + (v >> 2);   // consumer P slot

  // ---------------- warmup: items 0,1 (encoder windows 0,1) ----------------
  if (prod) {
    loadW(0);
    produce(0, 0);
    produce(0, 1);
  }
  __syncthreads();

  // ---------------- main: 32 windows (16 enc + 16 dec) ----------------
#pragma unroll 1
  for (int win = 0; win < 32; ++win) {
    if (prod) {
      const int item = win + 2;
      if (item < 32) produce(item >> 4, item & 15);
    } else {
      const int ph = win >> 4;
      const int w  = win & 15;
      const float* Pb = P + ((size_t)((ph << 10) + e) * TT) * 32 + pos_c;
      if (w == 0) {
        if (ph == 0) load_phase(eWihR, eWhh, eBih, eBhh);
        else         load_phase(dWihR, dWhh, dBih, dBhh);
        // preload t=0..7
#pragma unroll
        for (int k = 0; k < PF; ++k) pf[k] = Pb[k * 32];
        // peeled group t=0..7 (skew startup), refill 8..15
#pragma unroll
        for (int k = 0; k < PF; ++k) {
          float cur = pf[k];
          pf[k] = Pb[(k + PF) * 32];
          float n1 = lstep(IC<0>{}, cur);
          float n2 = 0.f;
          if (k >= 1) n2 = lstep(IC<1>{}, bd1);
          if (k >= 2) (void)lstep(IC<2>{}, bd2);
          bd1 = n1; bd2 = n2;
        }
        // groups consuming 8..15, 16..23, 24..31 (refill +8)
#pragma unroll 1
        for (int gi = 1; gi < 4; ++gi) {
          const float* Pq = Pb + (size_t)((gi + 1) * PF) * 32;
#pragma unroll
          for (int j = 0; j < PF; ++j) {
            float cur = pf[j];
            pf[j] = Pq[j * 32];
            float n1, n2;
            lstep3(cur, bd1, bd2, n1, n2);
            bd1 = n1; bd2 = n2;
          }
        }
      } else if (w < 15) {
        // 4 groups: consume 32w..32w+31, refill +8 each
#pragma unroll 1
        for (int gi = 0; gi < 4; ++gi) {
          const float* Pq = Pb + (size_t)(w * WBLK + gi * PF + PF) * 32;
#pragma unroll
          for (int j = 0; j < PF; ++j) {
            float cur = pf[j];
            pf[j] = Pq[j * 32];
            float n1, n2;
            lstep3(cur, bd1, bd2, n1, n2);
            bd1 = n1; bd2 = n2;
          }
        }
      } else {
        // w == 15: 3 refilled groups (480..503), final group 504..511, drain
#pragma unroll 1
        for (int gi = 0; gi < 3; ++gi) {
          const float* Pq = Pb + (size_t)(480 + gi * PF + PF) * 32;
#pragma unroll
          for (int j = 0; j < PF; ++j) {
            float cur = pf[j];
            pf[j] = Pq[j * 32];
            float n1, n2;
            lstep3(cur, bd1, bd2, n1, n2);
            bd1 = n1; bd2 = n2;
          }
        }
#pragma unroll
        for (int j = 0; j < PF; ++j) {
          float cur = pf[j];
          float n1, n2;
          lstep3(cur, bd1, bd2, n1, n2);
          bd1 = n1; bd2 = n2;
        }
        // drain skew: layer1 t=511, layer2 t=510, layer2 t=511
        float dd = lstep(IC<1>{}, bd1);
        (void)lstep(IC<2>{}, bd2);
        (void)lstep(IC<2>{}, dd);
      }
    }
    __syncthreads();
  }

  // epilogue: linear on final decoder layer-2 h (consumers only)
  if (!prod) {
    float lwA[4], lwB[4];
#pragma unroll
    for (int k = 0; k < 4; ++k) {
      const int col = (b + d * k) & 3;
      lwA[k] = linW[col];
      lwB[k] = linW[4 + col];
    }
    float A[4], Bv[4];
    bcast(H[2], A, Bv);
    float pred = linB[0];
#pragma unroll
    for (int k = 0; k < 4; ++k) {
      pred = fmaf(lwA[k], A[k],  pred);
      pred = fmaf(lwB[k], Bv[k], pred);
    }
    if (idx == 0) out[e] = pred;
  }
}

// ============================================================
// Fallback (ws too small): round-1 verified single-kernel version.
// ============================================================
__global__ __launch_bounds__(64) void seq2seq_fallback(
    const float* __restrict__ x, const float* __restrict__ h0, const float* __restrict__ c0,
    const float* __restrict__ eWih0, const float* __restrict__ eWihR, const float* __restrict__ eWhh,
    const float* __restrict__ eBih,  const float* __restrict__ eBhh,
    const float* __restrict__ dWih0, const float* __restrict__ dWihR, const float* __restrict__ dWhh,
    const float* __restrict__ dBih,  const float* __restrict__ dBhh,
    const float* __restrict__ linW,  const float* __restrict__ linB, float* __restrict__ out)
{
  const int tid = threadIdx.x;
  const int g   = tid & 31;
  const int grp = tid & 32;
  const int jj  = g & 7;
  const int e   = blockIdx.x * 2 + (tid >> 5);
  const bool is_tanh = ((g >> 3) == 2);
  const float s_act = is_tanh ? 2.885390082f : 1.44269504f;
  const float a_act = is_tanh ? 2.0f : 1.0f;
  const float b_act = is_tanh ? -1.0f : 0.0f;
  float hrep[3][8]; float cc[3];
#pragma unroll
  for (int l = 0; l < 3; ++l) {
#pragma unroll
    for (int k = 0; k < 8; ++k) hrep[l][k] = h0[((size_t)l * BB + e) * HH + k];
    cc[l] = c0[((size_t)l * BB + e) * HH + jj];
  }
  for (int p = 0; p < 2; ++p) {
    const float* Wih0 = p ? dWih0 : eWih0;  const float* WihR = p ? dWihR : eWihR;
    const float* Whh  = p ? dWhh  : eWhh;   const float* Bih  = p ? dBih  : eBih;
    const float* Bhh  = p ? dBhh  : eBhh;
    float Wx[64];
#pragma unroll
    for (int k = 0; k < 64; k += 4) {
      float4 w = *(const float4*)(Wih0 + g * 64 + k);
      Wx[k] = w.x; Wx[k+1] = w.y; Wx[k+2] = w.z; Wx[k+3] = w.w;
    }
    float Wh[3][8], Wi[2][8], bias[3];
#pragma unroll
    for (int l = 0; l < 3; ++l) {
#pragma unroll
      for (int k = 0; k < 8; ++k) Wh[l][k] = Whh[(l*32+g)*8+k];
      bias[l] = Bih[l*32+g] + Bhh[l*32+g];
    }
#pragma unroll
    for (int l = 0; l < 2; ++l)
#pragma unroll
      for (int k = 0; k < 8; ++k) Wi[l][k] = WihR[(l*32+g)*8+k];
    const float* xrow = x + (size_t)e * TT * DD;
    for (int t = 0; t < TT; ++t) {
      float4 acc = make_float4(bias[0], 0.f, 0.f, 0.f);
#pragma unroll
      for (int kc = 0; kc < 16; ++kc) {
        float4 xv = *(const float4*)(xrow + kc * 4);
        acc.x = fmaf(Wx[kc*4+0], xv.x, acc.x); acc.y = fmaf(Wx[kc*4+1], xv.y, acc.y);
        acc.z = fmaf(Wx[kc*4+2], xv.z, acc.z); acc.w = fmaf(Wx[kc*4+3], xv.w, acc.w);
      }
      float pre = (acc.x + acc.y) + (acc.z + acc.w);
      { float r0=0.f,r1=0.f;
#pragma unroll
        for (int k = 0; k < 8; k += 2) { r0=fmaf(Wh[0][k],hrep[0][k],r0); r1=fmaf(Wh[0][k+1],hrep[0][k+1],r1); }
        pre += r0 + r1; }
#pragma unroll
      for (int l = 0; l < 3; ++l) {
        if (l > 0) {
          float r0 = bias[l], r1 = 0.f;
#pragma unroll
          for (int k = 0; k < 8; k += 2) {
            r0=fmaf(Wi[l-1][k],hrep[l-1][k],r0); r1=fmaf(Wi[l-1][k+1],hrep[l-1][k+1],r1);
            r0=fmaf(Wh[l][k],hrep[l][k],r0);     r1=fmaf(Wh[l][k+1],hrep[l][k+1],r1);
          }
          pre = r0 + r1;
        }
        float act = fmaf(a_act, frcp(1.0f + fexp2(-s_act * pre)), b_act);
        float iv = __shfl(act, grp + jj);
        float fv = __shfl(act, grp + 8 + jj);
        float gv = __shfl(act, grp + 16 + jj);
        float ov = __shfl(act, grp + 24 + jj);
        float cn = fmaf(fv, cc[l], iv * gv);
        cc[l] = cn;
        float th = fmaf(2.0f, frcp(1.0f + fexp2(-2.885390082f * cn)), -1.0f);
        float hn = ov * th;
#pragma unroll
        for (int k = 0; k < 8; ++k) hrep[l][k] = __shfl(hn, grp + k);
      }
      xrow += DD;
    }
  }
  float pred = linB[0];
#pragma unroll
  for (int k = 0; k < 8; ++k) pred = fmaf(linW[k], hrep[2][k], pred);
  if (g == 0) out[e] = pred;
}

extern "C" void kernel_launch(void* const* d_in, const int* in_sizes, int n_in,
                              void* d_out, int out_size, void* d_ws, size_t ws_size,
                              hipStream_t stream) {
  const float* x     = (const float*)d_in[0];
  const float* h0    = (const float*)d_in[1];
  const float* c0    = (const float*)d_in[2];
  const float* eWih0 = (const float*)d_in[3];
  const float* eWihR = (const float*)d_in[4];
  const float* eWhh  = (const float*)d_in[5];
  const float* eBih  = (const float*)d_in[6];
  const float* eBhh  = (const float*)d_in[7];
  const float* dWih0 = (const float*)d_in[8];
  const float* dWihR = (const float*)d_in[9];
  const float* dWhh  = (const float*)d_in[10];
  const float* dBih  = (const float*)d_in[11];
  const float* dBhh  = (const float*)d_in[12];
  const float* linW  = (const float*)d_in[13];
  const float* linB  = (const float*)d_in[14];
  float* out = (float*)d_out;

  const size_t P_BYTES = (size_t)2 * BB * TT * 32 * sizeof(float);  // 128 MiB
  if (ws_size >= P_BYTES) {
    float* P = (float*)d_ws;
    // 96 KiB dynamic LDS: ~17 KiB used (producer staging) + padding to
    // force 1 block/CU (2 blocks would co-schedule consumers on one SIMD).
    fused_kernel<<<BB / 4, 256, 98304, stream>>>(
        x, h0, c0, eWih0, eWihR, eWhh, eBih, eBhh,
        dWih0, dWihR, dWhh, dBih, dBhh, linW, linB, P, out);
  } else {
    seq2seq_fallback<<<BB / 2, 64, 0, stream>>>(x, h0, c0, eWih0, eWihR, eWhh, eBih, eBhh,
                                                dWih0, dWihR, dWhh, dBih, dBhh, linW, linB, out);
  }
}